// Round 1
// baseline (175.532 us; speedup 1.0000x reference)
//
#include <hip/hip_runtime.h>

#define NN 1024
#define NP (NN * NN)

// ---------------- P1: LayerNorm + GEMV (x = LN(pair) @ W + b) ----------------
// 16 lanes per (i,j) pair, 8 channels per lane (channels 4l..4l+3 and 64+4l..64+4l+3).
__global__ __launch_bounds__(256) void k_ln_gemv(
    const float* __restrict__ pairp, const float* __restrict__ gamma,
    const float* __restrict__ beta, const float* __restrict__ W,
    const float* __restrict__ bvec, float* __restrict__ xout, int ngroups)
{
  const int l = threadIdx.x & 15;
  const int group = blockIdx.x * 16 + (threadIdx.x >> 4);

  // Per-lane constant slices (reused across grid-stride loop)
  float gam[8], bet[8], Wr[8][6];
#pragma unroll
  for (int k = 0; k < 2; ++k)
#pragma unroll
    for (int m = 0; m < 4; ++m) {
      const int c = 4 * l + 64 * k + m;
      const int idx = 4 * k + m;
      gam[idx] = gamma[c];
      bet[idx] = beta[c];
#pragma unroll
      for (int d = 0; d < 6; ++d) Wr[idx][d] = W[c * 6 + d];
    }
  const float bl = (l < 6) ? bvec[l] : 0.f;

  for (int p = group; p < NP; p += ngroups) {
    const float* base = pairp + (size_t)p * 128;
    const float4 xa = *(const float4*)(base + 4 * l);
    const float4 xb = *(const float4*)(base + 64 + 4 * l);

    float s = ((xa.x + xa.y) + (xa.z + xa.w)) + ((xb.x + xb.y) + (xb.z + xb.w));
    float sq = ((xa.x * xa.x + xa.y * xa.y) + (xa.z * xa.z + xa.w * xa.w)) +
               ((xb.x * xb.x + xb.y * xb.y) + (xb.z * xb.z + xb.w * xb.w));
#pragma unroll
    for (int m = 1; m <= 8; m <<= 1) {
      s += __shfl_xor(s, m);
      sq += __shfl_xor(sq, m);
    }
    const float mu = s * (1.f / 128.f);
    const float var = sq * (1.f / 128.f) - mu * mu;
    const float rstd = rsqrtf(var + 1e-5f);
    const float nmr = -mu * rstd;

    const float xv[8] = {xa.x, xa.y, xa.z, xa.w, xb.x, xb.y, xb.z, xb.w};
    float acc[6] = {0, 0, 0, 0, 0, 0};
#pragma unroll
    for (int k = 0; k < 8; ++k) {
      const float h = fmaf(fmaf(xv[k], rstd, nmr), gam[k], bet[k]);
#pragma unroll
      for (int d = 0; d < 6; ++d) acc[d] = fmaf(h, Wr[k][d], acc[d]);
    }
#pragma unroll
    for (int d = 0; d < 6; ++d)
#pragma unroll
      for (int m = 1; m <= 8; m <<= 1) acc[d] += __shfl_xor(acc[d], m);

    if (l < 6) {
      const float v = (l == 0) ? acc[0] : (l == 1) ? acc[1] : (l == 2) ? acc[2]
                     : (l == 3) ? acc[3] : (l == 4) ? acc[4] : acc[5];
      xout[(size_t)p * 6 + l] = v + bl;  // lanes of a wave write contiguous 96B
    }
  }
}

// ---------------- P2: row LSE (== col LSE by symmetry of xs) ----------------
// lse[i,d] = log(1 + sum_j exp(xs[i,j,d])); masked entries exp(-1e6)=0.
__global__ __launch_bounds__(256) void k_row_lse(
    const float* __restrict__ x, const int* __restrict__ seq,
    float* __restrict__ lse)
{
  const int i = blockIdx.x;
  const int tid = threadIdx.x;
  const int si = seq[i];
  float sm[6] = {0, 0, 0, 0, 0, 0};

  for (int j = tid; j < NN; j += 256) {
    const int dd = si - seq[j];
    const bool far = (dd > 3) || (dd < -3);
    const float* a = x + ((size_t)i * NN + j) * 6;
    const float* c = x + ((size_t)j * NN + i) * 6;
    const float2 a0 = *(const float2*)(a);
    const float2 a1 = *(const float2*)(a + 2);
    const float2 a2 = *(const float2*)(a + 4);
    const float2 c0 = *(const float2*)(c);
    const float2 c1 = *(const float2*)(c + 2);
    const float2 c2 = *(const float2*)(c + 4);
    const float xs0 = far ? 0.5f * (a0.x + c0.x) : -1000000.0f;
    const float xs1 = far ? 0.5f * (a0.y + c0.y) : -1000000.0f;
    const float xs2 = far ? 0.5f * (a1.x + c1.x) : -1000000.0f;
    const float xs3 = far ? 0.5f * (a1.y + c1.y) : -1000000.0f;
    const float xs4 = far ? 0.5f * (a2.x + c2.x) : -1000000.0f;
    const float xs5 = far ? 0.5f * (a2.y + c2.y) : -1000000.0f;
    sm[0] += __expf(xs0);
    sm[1] += __expf(xs1);
    sm[2] += __expf(xs2);
    sm[3] += __expf(xs3);
    sm[4] += __expf(xs4);
    sm[5] += __expf(xs5);
  }
#pragma unroll
  for (int d = 0; d < 6; ++d)
#pragma unroll
    for (int m = 1; m <= 32; m <<= 1) sm[d] += __shfl_xor(sm[d], m);

  __shared__ float red[4][6];
  const int w = tid >> 6;
  if ((tid & 63) == 0) {
#pragma unroll
    for (int d = 0; d < 6; ++d) red[w][d] = sm[d];
  }
  __syncthreads();
  if (tid < 6) {
    const float t = red[0][tid] + red[1][tid] + red[2][tid] + red[3][tid];
    lse[i * 6 + tid] = logf(1.f + t);
  }
}

// ---------------- P3: out = 4*xs - lse[i] - lse[j] - 2*chn_lse ----------------
__global__ __launch_bounds__(256) void k_out(
    const float* __restrict__ x, const int* __restrict__ seq,
    const float* __restrict__ lse, float* __restrict__ out)
{
  const int p = blockIdx.x * 256 + threadIdx.x;
  const int i = p >> 10;
  const int j = p & (NN - 1);
  const int dd = seq[i] - seq[j];
  const bool far = (dd > 3) || (dd < -3);

  const float* a = x + (size_t)p * 6;
  const float* c = x + ((size_t)j * NN + i) * 6;
  const float2 a0 = *(const float2*)(a);
  const float2 a1 = *(const float2*)(a + 2);
  const float2 a2 = *(const float2*)(a + 4);
  const float2 c0 = *(const float2*)(c);
  const float2 c1 = *(const float2*)(c + 2);
  const float2 c2 = *(const float2*)(c + 4);

  float xs[6];
  xs[0] = far ? 0.5f * (a0.x + c0.x) : -1000000.0f;
  xs[1] = far ? 0.5f * (a0.y + c0.y) : -1000000.0f;
  xs[2] = far ? 0.5f * (a1.x + c1.x) : -1000000.0f;
  xs[3] = far ? 0.5f * (a1.y + c1.y) : -1000000.0f;
  xs[4] = far ? 0.5f * (a2.x + c2.x) : -1000000.0f;
  xs[5] = far ? 0.5f * (a2.y + c2.y) : -1000000.0f;

  float ssum = 0.f;
#pragma unroll
  for (int d = 0; d < 6; ++d) ssum += __expf(xs[d]);
  const float lc2 = 2.f * logf(1.f + ssum);

  const float* li = lse + i * 6;
  const float* lj = lse + j * 6;
  float o[6];
#pragma unroll
  for (int d = 0; d < 6; ++d) o[d] = 4.f * xs[d] - li[d] - lj[d] - lc2;

  float* op = out + (size_t)p * 6;
  *(float2*)(op) = make_float2(o[0], o[1]);
  *(float2*)(op + 2) = make_float2(o[2], o[3]);
  *(float2*)(op + 4) = make_float2(o[4], o[5]);
}

extern "C" void kernel_launch(void* const* d_in, const int* in_sizes, int n_in,
                              void* d_out, int out_size, void* d_ws, size_t ws_size,
                              hipStream_t stream) {
  const float* pairp = (const float*)d_in[0];
  const int* seq = (const int*)d_in[1];
  const float* gamma = (const float*)d_in[2];
  const float* beta = (const float*)d_in[3];
  const float* W = (const float*)d_in[4];
  const float* bvec = (const float*)d_in[5];
  float* out = (float*)d_out;

  float* x = (float*)d_ws;                  // 1024*1024*6 fp32 = 24 MB
  float* lse = x + (size_t)NP * 6;          // 1024*6 fp32

  k_ln_gemv<<<2048, 256, 0, stream>>>(pairp, gamma, beta, W, bvec, x, 2048 * 16);
  k_row_lse<<<NN, 256, 0, stream>>>(x, seq, lse);
  k_out<<<NP / 256, 256, 0, stream>>>(x, seq, lse, out);
}